// Round 23
// baseline (201.298 us; speedup 1.0000x reference)
//
#include <hip/hip_runtime.h>
#include <cstdint>

// CausalSelfAttention fused pipeline, all-bf16 MFMA path.
// R22 = R21 minus defer-max (single-variable isolation: R21 bundled P-swizzle +
// defer-max + relconv; attn regressed 104.4->107.3 while conflicts DROPPED, so
// defer-max's per-tile __any+branch in the serial chain is the prime suspect —
// T13's win requires a large rescale cost; ours is ~20 VALU ops).
// Keeps: swapped-QK^T body, exp2 softmax, 4-batch-wave grid, relt L1-sharing,
// P-LDS stride-64 XOR-chunk swizzle, coalesced relconv.
// ws layout (ushort): Qf[8.39M] Kf[8.39M] Vf[8.39M] XbAO[8.39M] WtQ[786K] WtO[262K] [relt 33.55M]

#define DEVI __device__ __forceinline__

typedef __bf16 bf8 __attribute__((ext_vector_type(8)));
typedef float f4 __attribute__((ext_vector_type(4)));
typedef unsigned short us8 __attribute__((ext_vector_type(8)));
typedef unsigned short us4 __attribute__((ext_vector_type(4)));

typedef const unsigned int __attribute__((address_space(1))) gu32;
typedef unsigned int __attribute__((address_space(3))) lu32;

#define L2E 1.44269504088896f

DEVI unsigned short f2bf(float f) {  // RNE f32->bf16 (prep/GEMM epilogues)
  unsigned u = __builtin_bit_cast(unsigned, f);
  u += 0x7fffu + ((u >> 16) & 1u);
  return (unsigned short)(u >> 16);
}

DEVI unsigned short cbf(float f) {   // compiler-lowered cast (v_cvt_pk_bf16_f32 pairs)
  return __builtin_bit_cast(unsigned short, (__bf16)f);
}

DEVI void gl_lds16(const void* g, void* l) {
  __builtin_amdgcn_global_load_lds((gu32*)g, (lu32*)l, 16, 0, 0);
}

// ---------------- prep: x (f32 [16384][512]) -> bf16, chunk-swizzled ----------------
__global__ __launch_bounds__(256) void k_convert_x(const float* __restrict__ x,
                                                   unsigned short* __restrict__ xb) {
  int c = blockIdx.x * 256 + threadIdx.x;   // 1,048,576 chunks
  int row = c >> 6, cl = c & 63;
  const float* s = x + ((size_t)row << 9) + (cl << 3);
  float4 a = *(const float4*)s;
  float4 b = *(const float4*)(s + 4);
  us8 o;
  o[0]=f2bf(a.x); o[1]=f2bf(a.y); o[2]=f2bf(a.z); o[3]=f2bf(a.w);
  o[4]=f2bf(b.x); o[5]=f2bf(b.y); o[6]=f2bf(b.z); o[7]=f2bf(b.w);
  int p = (cl & ~7) | ((cl & 7) ^ (row & 7));
  *(us8*)(xb + ((size_t)row << 9) + (p << 3)) = o;
}

// ------------- prep: W [512][N] f32 -> Wt [N][512] bf16, chunk-swizzled -------------
__global__ __launch_bounds__(256) void k_transpose_w(const float* __restrict__ W,
                                                     unsigned short* __restrict__ Wt, int N) {
  __shared__ float t[32][33];
  int k0 = blockIdx.x * 32, n0 = blockIdx.y * 32;
  int tx = threadIdx.x & 31, ty = threadIdx.x >> 5;
#pragma unroll
  for (int r = 0; r < 4; ++r)
    t[ty + r * 8][tx] = W[(size_t)(k0 + ty + r * 8) * N + n0 + tx];
  __syncthreads();
#pragma unroll
  for (int r = 0; r < 4; ++r) {
    int n = n0 + ty + r * 8, k = k0 + tx;
    int k2 = (k & ~63) | ((((k >> 3) & 7) ^ (n & 7)) << 3) | (k & 7);
    Wt[((size_t)n << 9) + k2] = f2bf(t[tx][ty + r * 8]);
  }
}

// ---- prep: rel f32 [h][q][k] -> bf16 table, SWAPPED frag order, PRE-SCALED by log2e ----
// One WAVE per (h,q16,kt) tile: coalesced 16x(256B) row reads -> wave-private LDS
// -> transpose reads -> coalesced us4 writes.
__global__ __launch_bounds__(256) void k_relconv(const float* __restrict__ rel,
                                                 unsigned short* __restrict__ relt) {
  __shared__ __align__(16) float tl[4][16][68];
  int wv = threadIdx.x >> 6, lane = threadIdx.x & 63;
  int t = blockIdx.x * 4 + wv;              // 32768 tiles
  int kt = t & 31, q16 = (t >> 5) & 127, h = t >> 12;
  if (kt > (q16 >> 2)) return;              // above-diagonal tiles never read
  const float* src = rel + ((size_t)h << 22) +
                     ((size_t)((q16 << 4) + (lane >> 2)) << 11) + (kt << 6) + (lane & 3) * 16;
  float4 v0 = *(const float4*)(src);
  float4 v1 = *(const float4*)(src + 4);
  float4 v2 = *(const float4*)(src + 8);
  float4 v3 = *(const float4*)(src + 12);
  float* dst = &tl[wv][lane >> 2][(lane & 3) * 16];
  *(float4*)(dst) = v0; *(float4*)(dst + 4) = v1;
  *(float4*)(dst + 8) = v2; *(float4*)(dst + 12) = v3;
  size_t tb = (((((size_t)h << 7) | q16) << 5) | kt) << 2;
#pragma unroll
  for (int ct = 0; ct < 4; ++ct) {
    const float* rp = &tl[wv][lane & 15][ct * 16 + ((lane >> 4) << 2)];
    float4 rv = *(const float4*)rp;
    us4 o;
    o[0] = f2bf(rv.x * L2E); o[1] = f2bf(rv.y * L2E);
    o[2] = f2bf(rv.z * L2E); o[3] = f2bf(rv.w * L2E);
    *(us4*)(relt + (((tb | ct) << 6) | lane) * 4) = o;
  }
}

// ---------------- GEMM: C[M][col] = A[M][512] * Bt[col][512]^T + bias ----------------
template <int EPI>
__global__ __launch_bounds__(256, 2)
void k_gemm(const unsigned short* __restrict__ Ag, const unsigned short* __restrict__ Bg,
            const float* __restrict__ bias, float* __restrict__ Of,
            unsigned short* __restrict__ Oq, unsigned short* __restrict__ Ok,
            unsigned short* __restrict__ Ov) {
  __shared__ __align__(16) unsigned short lds[128 * 64 * 2];
  unsigned short* Al = lds;
  unsigned short* Bl = lds + 128 * 64;
  const int tid = threadIdx.x, wv = tid >> 6, lane = tid & 63, g = lane >> 4, cl = lane & 15;
  const int wm = wv >> 1, wn = wv & 1;
  const int row0 = blockIdx.x * 128, col0 = blockIdx.y * 128;
  f4 acc[4][4];
#pragma unroll
  for (int i = 0; i < 4; ++i)
#pragma unroll
    for (int j = 0; j < 4; ++j) acc[i][j] = (f4){0.f, 0.f, 0.f, 0.f};

  for (int kt = 0; kt < 8; ++kt) {
#pragma unroll
    for (int j = 0; j < 4; ++j) {
      int ci = wv * 4 + j;
      int gci = ci * 64 + lane;
      int r = gci >> 3, cc = gci & 7;
      gl_lds16(Ag + ((size_t)(row0 + r) << 9) + kt * 64 + cc * 8, Al + ci * 512);
      gl_lds16(Bg + ((size_t)(col0 + r) << 9) + kt * 64 + cc * 8, Bl + ci * 512);
    }
    __syncthreads();
#pragma unroll
    for (int kk = 0; kk < 2; ++kk) {
      bf8 af[4], bb[4];
#pragma unroll
      for (int mf = 0; mf < 4; ++mf) {
        int r = wm * 64 + mf * 16 + cl;
        int cc = (kk * 4 + g) ^ (r & 7);
        af[mf] = *(const bf8*)(Al + r * 64 + cc * 8);
      }
#pragma unroll
      for (int nf = 0; nf < 4; ++nf) {
        int r = wn * 64 + nf * 16 + cl;
        int cc = (kk * 4 + g) ^ (r & 7);
        bb[nf] = *(const bf8*)(Bl + r * 64 + cc * 8);
      }
#pragma unroll
      for (int mf = 0; mf < 4; ++mf)
#pragma unroll
        for (int nf = 0; nf < 4; ++nf)
          acc[mf][nf] = __builtin_amdgcn_mfma_f32_16x16x32_bf16(af[mf], bb[nf], acc[mf][nf], 0, 0, 0);
    }
    __syncthreads();
  }

  if (EPI == 1) {
#pragma unroll
    for (int nf = 0; nf < 4; ++nf) {
      int col = col0 + wn * 64 + nf * 16 + cl;
      float bv = bias[col];
#pragma unroll
      for (int mf = 0; mf < 4; ++mf) {
#pragma unroll
        for (int j = 0; j < 4; ++j) {
          int row = row0 + wm * 64 + mf * 16 + 4 * g + j;  // C/D: col=lane&15, row=4*(lane>>4)+reg
          Of[((size_t)row << 9) + col] = acc[mf][nf][j] + bv;
        }
      }
    }
  } else {
    const int which = col0 >> 9;   // block-uniform
#pragma unroll
    for (int nf = 0; nf < 4; ++nf) {
      int col = col0 + wn * 64 + nf * 16 + cl;
      float bv = bias[col];
      int d = col & 63, h = (col >> 6) & 7;
#pragma unroll
      for (int mf = 0; mf < 4; ++mf) {
        int row = row0 + wm * 64 + mf * 16 + 4 * g;   // j = 0 row
        int b = row >> 11, s = row & 2047;
        size_t fb = ((size_t)b * 8 + h) * 131072;     // per-(b,h) fragment array
        if (which == 0) {
          // Q frag: [q16][kk][lane][8]; scale folds softmax 1/8 AND log2(e)
#pragma unroll
          for (int j = 0; j < 4; ++j) {
            int ss = s + j;
            size_t off = fb + (size_t)((ss >> 4) * 1024 + (d >> 5) * 512 +
                                       (((d >> 3) & 3) * 16 + (ss & 15)) * 8 + (d & 7));
            Oq[off] = f2bf((acc[mf][nf][j] + bv) * (0.125f * L2E));
          }
        } else if (which == 1) {
          // K frag: [kt][kk][ct][lane][8]
#pragma unroll
          for (int j = 0; j < 4; ++j) {
            int ss = s + j;
            size_t off = fb + (size_t)((ss >> 6) * 4096 + (d >> 5) * 2048 + ((ss >> 4) & 3) * 512 +
                                       (((d >> 3) & 3) * 16 + (ss & 15)) * 8 + (d & 7));
            Ok[off] = f2bf(acc[mf][nf][j] + bv);
          }
        } else {
          // V frag: [kt][kk][ct][lane][8]
          us4 o;
#pragma unroll
          for (int j = 0; j < 4; ++j) o[j] = f2bf(acc[mf][nf][j] + bv);
          size_t off = fb + (size_t)((s >> 6) * 4096 + ((s >> 5) & 1) * 2048 + (d >> 4) * 512 +
                                     ((((s >> 3) & 3) * 16) + (d & 15)) * 8 + (s & 7));
          *(us4*)(Ov + off) = o;
        }
      }
    }
  }
}

// ------------------------------- flash attention --------------------------------
// block = 4 waves = 4 BATCHES of the same (h, q16) slab; 2048 blocks big-first.
// SWAPPED tile body (lane owns q-row), exp2 softmax (unconditional rescale),
// P via XOR-chunk-swizzled LDS rows (stride 64, 16B aligned).
template <bool RELT>
__global__ __launch_bounds__(256, 4)
void k_attn(const unsigned short* __restrict__ Qf, const unsigned short* __restrict__ Kf,
            const unsigned short* __restrict__ Vf, const float* __restrict__ rel,
            const unsigned short* __restrict__ relt, unsigned short* __restrict__ AO) {
  __shared__ __align__(16) unsigned short Pl[4][16 * 64];
  const int tid = threadIdx.x, wv = tid >> 6, lane = tid & 63, g = lane >> 4, cl = lane & 15;
  int bid = blockIdx.x;                        // 2048 blocks
  int h = bid & 7;                             // head's relt panel pinned to one XCD
  int rest = bid >> 3;                         // 0..255
  int q16 = 127 - (rest >> 1);                 // 127..0, big-first
  int b = ((rest & 1) << 2) | wv;              // 0..7
  const int rX = q16 << 4;
  const int ktop = q16 >> 2;                   // diagonal k-tile index
  const int qrow = rX + cl;                    // this lane's q-row (swapped layout)
  size_t fb = (((size_t)b << 3) + h) * 131072;
  const unsigned short* Qp = Qf + fb;
  const unsigned short* Kp = Kf + fb;
  const unsigned short* Vp = Vf + fb;
  const float* relp = rel + ((size_t)h << 22);
  unsigned short* pw = Pl[wv];

  bf8 qf[2];
#pragma unroll
  for (int kk = 0; kk < 2; ++kk)
    qf[kk] = *(const bf8*)(Qp + q16 * 1024 + kk * 512 + lane * 8);

  f4 ot[4];                                    // O^T frags: ot[ct][j] = O[q=cl][d=16ct+4g+j]
  float mr = -1e30f, lr = 0.f;
#pragma unroll
  for (int ct = 0; ct < 4; ++ct) ot[ct] = (f4){0.f, 0.f, 0.f, 0.f};

  for (int kt = 0; kt <= ktop; ++kt) {
    const int kb = kt << 6;
    const unsigned short* Kt = Kp + kt * 4096;
    const unsigned short* Vt = Vp + kt * 4096;
    // ---- ALL loads up front: K (QK^T dep), then V, then rel (FIFO vmcnt) ----
    bf8 kf[2][4], vf[2][4];
#pragma unroll
    for (int kk = 0; kk < 2; ++kk)
#pragma unroll
      for (int ct = 0; ct < 4; ++ct)
        kf[kk][ct] = *(const bf8*)(Kt + kk * 2048 + ct * 512 + lane * 8);
#pragma unroll
    for (int kk = 0; kk < 2; ++kk)
#pragma unroll
      for (int ct = 0; ct < 4; ++ct)
        vf[kk][ct] = *(const bf8*)(Vt + kk * 2048 + ct * 512 + lane * 8);
    us4 rt4[4];
    float4 rl4[4];
    if constexpr (RELT) {
      const unsigned short* tb = relt + (((((size_t)h << 7) | q16) << 5) | kt) * 1024;
#pragma unroll
      for (int ct = 0; ct < 4; ++ct)
        rt4[ct] = *(const us4*)(tb + ((ct << 6) | lane) * 4);
    } else {
#pragma unroll
      for (int ct = 0; ct < 4; ++ct)
        rl4[ct] = *(const float4*)(relp + ((size_t)qrow << 11) + kb + ct * 16 + g * 4);
    }
    // ---- QK^T SWAPPED: st[ct][j] = S[q=cl][k = kb + 16ct + 4g + j] ----
    f4 st[4];
#pragma unroll
    for (int ct = 0; ct < 4; ++ct) st[ct] = (f4){0.f, 0.f, 0.f, 0.f};
#pragma unroll
    for (int kk = 0; kk < 2; ++kk)
#pragma unroll
      for (int ct = 0; ct < 4; ++ct)
        st[ct] = __builtin_amdgcn_mfma_f32_16x16x32_bf16(kf[kk][ct], qf[kk], st[ct], 0, 0, 0);
    // ---- rel_pos add (already in log2e domain) ----
    if constexpr (RELT) {
#pragma unroll
      for (int ct = 0; ct < 4; ++ct)
#pragma unroll
        for (int j = 0; j < 4; ++j)
          st[ct][j] += __builtin_bit_cast(float, (unsigned)rt4[ct][j] << 16);
    } else {
#pragma unroll
      for (int ct = 0; ct < 4; ++ct) {
        st[ct][0] = fmaf(rl4[ct].x, L2E, st[ct][0]);
        st[ct][1] = fmaf(rl4[ct].y, L2E, st[ct][1]);
        st[ct][2] = fmaf(rl4[ct].z, L2E, st[ct][2]);
        st[ct][3] = fmaf(rl4[ct].w, L2E, st[ct][3]);
      }
    }
    // ---- causal mask (diagonal tile only) ----
    if (kt == ktop) {
#pragma unroll
      for (int ct = 0; ct < 4; ++ct) {
        int kc0 = kb + ct * 16 + 4 * g;
#pragma unroll
        for (int j = 0; j < 4; ++j)
          if (kc0 + j > qrow) st[ct][j] = -1e30f;
      }
    }
    // ---- online softmax (exp2 domain, unconditional rescale) ----
    float m0 = fmaxf(fmaxf(st[0][0], st[0][1]), fmaxf(st[0][2], st[0][3]));
#pragma unroll
    for (int ct = 1; ct < 4; ++ct)
      m0 = fmaxf(m0, fmaxf(fmaxf(st[ct][0], st[ct][1]), fmaxf(st[ct][2], st[ct][3])));
    m0 = fmaxf(m0, __shfl_xor(m0, 16));
    m0 = fmaxf(m0, __shfl_xor(m0, 32));
    float mn = fmaxf(mr, m0);
    float al = exp2f(mr - mn);
    mr = mn;
#pragma unroll
    for (int ct = 0; ct < 4; ++ct)
#pragma unroll
      for (int j = 0; j < 4; ++j) st[ct][j] = exp2f(st[ct][j] - mn);
    float rs = 0.f;
#pragma unroll
    for (int ct = 0; ct < 4; ++ct)
      rs += (st[ct][0] + st[ct][1]) + (st[ct][2] + st[ct][3]);
    rs += __shfl_xor(rs, 16);
    rs += __shfl_xor(rs, 32);
    lr = lr * al + rs;
#pragma unroll
    for (int ct = 0; ct < 4; ++ct) {
      ot[ct][0] *= al; ot[ct][1] *= al; ot[ct][2] *= al; ot[ct][3] *= al;
    }
    // ---- P -> LDS rows [q=cl], XOR-chunk swizzled (stride 64) ----
#pragma unroll
    for (int ct = 0; ct < 4; ++ct) {
      us4 pk;
      pk[0] = cbf(st[ct][0]); pk[1] = cbf(st[ct][1]);
      pk[2] = cbf(st[ct][2]); pk[3] = cbf(st[ct][3]);
      *(us4*)(pw + cl * 64 + (((2 * ct + (g >> 1)) ^ (cl & 7)) << 3) + ((g & 1) << 2)) = pk;
    }
    // ---- PV SWAPPED: read chunk 4kk+g (swz ^(cl&7)) as B-frag b128 ----
#pragma unroll
    for (int kk = 0; kk < 2; ++kk) {
      bf8 pf = __builtin_bit_cast(bf8,
                 *(const us8*)(pw + cl * 64 + (((4 * kk + g) ^ (cl & 7)) << 3)));
#pragma unroll
      for (int ct = 0; ct < 4; ++ct)
        ot[ct] = __builtin_amdgcn_mfma_f32_16x16x32_bf16(vf[kk][ct], pf, ot[ct], 0, 0, 0);
    }
  }
  // ---- epilogue: O /= l; d = 16ct+4g+j -> chunk-swizzled us4 stores ----
  float inv = 1.0f / lr;
  const int s = qrow;
  unsigned short* aor = AO + (((size_t)b << 11) + s) * 512 + h * 64;
#pragma unroll
  for (int ct = 0; ct < 4; ++ct) {
    int chunk = 2 * ct + (g >> 1);
    int base = (4 * (g & 1)) | ((chunk ^ (s & 7)) << 3);
    us4 o;
    o[0] = cbf(ot[ct][0] * inv); o[1] = cbf(ot[ct][1] * inv);
    o[2] = cbf(ot[ct][2] * inv); o[3] = cbf(ot[ct][3] * inv);
    *(us4*)(aor + base) = o;
  }
}

// ------------------------------------ launch ------------------------------------
extern "C" void kernel_launch(void* const* d_in, const int* in_sizes, int n_in,
                              void* d_out, int out_size, void* d_ws, size_t ws_size,
                              hipStream_t stream) {
  const float* x    = (const float*)d_in[0];
  const float* Wqkv = (const float*)d_in[1];
  const float* bqkv = (const float*)d_in[2];
  const float* Wout = (const float*)d_in[3];
  const float* bout = (const float*)d_in[4];
  const float* rel  = (const float*)d_in[5];
  float* out = (float*)d_out;

  unsigned short* Qw  = (unsigned short*)d_ws;
  unsigned short* Kw  = Qw  + 8388608;
  unsigned short* Vw  = Kw  + 8388608;
  unsigned short* XA  = Vw  + 8388608;    // Xb (pre-attn) then AO (post-attn)
  unsigned short* WtQ = XA  + 8388608;
  unsigned short* WtO = WtQ + 786432;
  unsigned short* relt= WtO + 262144;
  const bool useT = ws_size >= (34603008ULL + 33554432ULL) * 2ULL;  // base + rel table

  k_convert_x<<<dim3(4096), dim3(256), 0, stream>>>(x, XA);
  k_transpose_w<<<dim3(16, 48), dim3(256), 0, stream>>>(Wqkv, WtQ, 1536);
  k_transpose_w<<<dim3(16, 16), dim3(256), 0, stream>>>(Wout, WtO, 512);
  if (useT) k_relconv<<<dim3(8192), dim3(256), 0, stream>>>(rel, relt);
  k_gemm<0><<<dim3(128, 12), dim3(256), 0, stream>>>(XA, WtQ, bqkv, nullptr, Qw, Kw, Vw);
  if (useT) k_attn<true ><<<dim3(2048), dim3(256), 0, stream>>>(Qw, Kw, Vw, rel, relt, XA);
  else      k_attn<false><<<dim3(2048), dim3(256), 0, stream>>>(Qw, Kw, Vw, rel, relt, XA);
  k_gemm<1><<<dim3(128, 4), dim3(256), 0, stream>>>(XA, WtO, bout, out, nullptr, nullptr, nullptr);
}

// Round 24
// 196.513 us; speedup vs baseline: 1.0244x; 1.0244x over previous
//
#include <hip/hip_runtime.h>
#include <cstdint>

// CausalSelfAttention fused pipeline, all-bf16 MFMA path.
// R24 = measured-best parts composed (R20/R21/R23 isolation matrix):
//  - P-LDS stride-72 rows (R20): 4 ds_write_b64 share one addr reg + offset:
//    immediates; reads only 2-way bank-aliased (free, m136). The R21 XOR
//    swizzle cut counted conflicts but ADDED ~12 VALU addr ops in the chain
//    (+5.3us) — counted conflict-cycles are not exposed cycles.
//  - defer-max (R21): measured -2.4us (R21 vs R23, same base).
//  - coalesced relconv (R21), exp2 softmax (R20), 4-batch-wave grid (R15).
// ws layout (ushort): Qf[8.39M] Kf[8.39M] Vf[8.39M] XbAO[8.39M] WtQ[786K] WtO[262K] [relt 33.55M]

#define DEVI __device__ __forceinline__

typedef __bf16 bf8 __attribute__((ext_vector_type(8)));
typedef float f4 __attribute__((ext_vector_type(4)));
typedef unsigned short us8 __attribute__((ext_vector_type(8)));
typedef unsigned short us4 __attribute__((ext_vector_type(4)));

typedef const unsigned int __attribute__((address_space(1))) gu32;
typedef unsigned int __attribute__((address_space(3))) lu32;

#define L2E 1.44269504088896f

DEVI unsigned short f2bf(float f) {  // RNE f32->bf16 (prep/GEMM epilogues)
  unsigned u = __builtin_bit_cast(unsigned, f);
  u += 0x7fffu + ((u >> 16) & 1u);
  return (unsigned short)(u >> 16);
}

DEVI unsigned short cbf(float f) {   // compiler-lowered cast (v_cvt_pk_bf16_f32 pairs)
  return __builtin_bit_cast(unsigned short, (__bf16)f);
}

DEVI void gl_lds16(const void* g, void* l) {
  __builtin_amdgcn_global_load_lds((gu32*)g, (lu32*)l, 16, 0, 0);
}

// ---------------- prep: x (f32 [16384][512]) -> bf16, chunk-swizzled ----------------
__global__ __launch_bounds__(256) void k_convert_x(const float* __restrict__ x,
                                                   unsigned short* __restrict__ xb) {
  int c = blockIdx.x * 256 + threadIdx.x;   // 1,048,576 chunks
  int row = c >> 6, cl = c & 63;
  const float* s = x + ((size_t)row << 9) + (cl << 3);
  float4 a = *(const float4*)s;
  float4 b = *(const float4*)(s + 4);
  us8 o;
  o[0]=f2bf(a.x); o[1]=f2bf(a.y); o[2]=f2bf(a.z); o[3]=f2bf(a.w);
  o[4]=f2bf(b.x); o[5]=f2bf(b.y); o[6]=f2bf(b.z); o[7]=f2bf(b.w);
  int p = (cl & ~7) | ((cl & 7) ^ (row & 7));
  *(us8*)(xb + ((size_t)row << 9) + (p << 3)) = o;
}

// ------------- prep: W [512][N] f32 -> Wt [N][512] bf16, chunk-swizzled -------------
__global__ __launch_bounds__(256) void k_transpose_w(const float* __restrict__ W,
                                                     unsigned short* __restrict__ Wt, int N) {
  __shared__ float t[32][33];
  int k0 = blockIdx.x * 32, n0 = blockIdx.y * 32;
  int tx = threadIdx.x & 31, ty = threadIdx.x >> 5;
#pragma unroll
  for (int r = 0; r < 4; ++r)
    t[ty + r * 8][tx] = W[(size_t)(k0 + ty + r * 8) * N + n0 + tx];
  __syncthreads();
#pragma unroll
  for (int r = 0; r < 4; ++r) {
    int n = n0 + ty + r * 8, k = k0 + tx;
    int k2 = (k & ~63) | ((((k >> 3) & 7) ^ (n & 7)) << 3) | (k & 7);
    Wt[((size_t)n << 9) + k2] = f2bf(t[tx][ty + r * 8]);
  }
}

// ---- prep: rel f32 [h][q][k] -> bf16 table, SWAPPED frag order, PRE-SCALED by log2e ----
// One WAVE per (h,q16,kt) tile: coalesced 16x(256B) row reads -> wave-private LDS
// -> transpose reads -> coalesced us4 writes.
__global__ __launch_bounds__(256) void k_relconv(const float* __restrict__ rel,
                                                 unsigned short* __restrict__ relt) {
  __shared__ __align__(16) float tl[4][16][68];
  int wv = threadIdx.x >> 6, lane = threadIdx.x & 63;
  int t = blockIdx.x * 4 + wv;              // 32768 tiles
  int kt = t & 31, q16 = (t >> 5) & 127, h = t >> 12;
  if (kt > (q16 >> 2)) return;              // above-diagonal tiles never read
  const float* src = rel + ((size_t)h << 22) +
                     ((size_t)((q16 << 4) + (lane >> 2)) << 11) + (kt << 6) + (lane & 3) * 16;
  float4 v0 = *(const float4*)(src);
  float4 v1 = *(const float4*)(src + 4);
  float4 v2 = *(const float4*)(src + 8);
  float4 v3 = *(const float4*)(src + 12);
  float* dst = &tl[wv][lane >> 2][(lane & 3) * 16];
  *(float4*)(dst) = v0; *(float4*)(dst + 4) = v1;
  *(float4*)(dst + 8) = v2; *(float4*)(dst + 12) = v3;
  size_t tb = (((((size_t)h << 7) | q16) << 5) | kt) << 2;
#pragma unroll
  for (int ct = 0; ct < 4; ++ct) {
    const float* rp = &tl[wv][lane & 15][ct * 16 + ((lane >> 4) << 2)];
    float4 rv = *(const float4*)rp;
    us4 o;
    o[0] = f2bf(rv.x * L2E); o[1] = f2bf(rv.y * L2E);
    o[2] = f2bf(rv.z * L2E); o[3] = f2bf(rv.w * L2E);
    *(us4*)(relt + (((tb | ct) << 6) | lane) * 4) = o;
  }
}

// ---------------- GEMM: C[M][col] = A[M][512] * Bt[col][512]^T + bias ----------------
template <int EPI>
__global__ __launch_bounds__(256, 2)
void k_gemm(const unsigned short* __restrict__ Ag, const unsigned short* __restrict__ Bg,
            const float* __restrict__ bias, float* __restrict__ Of,
            unsigned short* __restrict__ Oq, unsigned short* __restrict__ Ok,
            unsigned short* __restrict__ Ov) {
  __shared__ __align__(16) unsigned short lds[128 * 64 * 2];
  unsigned short* Al = lds;
  unsigned short* Bl = lds + 128 * 64;
  const int tid = threadIdx.x, wv = tid >> 6, lane = tid & 63, g = lane >> 4, cl = lane & 15;
  const int wm = wv >> 1, wn = wv & 1;
  const int row0 = blockIdx.x * 128, col0 = blockIdx.y * 128;
  f4 acc[4][4];
#pragma unroll
  for (int i = 0; i < 4; ++i)
#pragma unroll
    for (int j = 0; j < 4; ++j) acc[i][j] = (f4){0.f, 0.f, 0.f, 0.f};

  for (int kt = 0; kt < 8; ++kt) {
#pragma unroll
    for (int j = 0; j < 4; ++j) {
      int ci = wv * 4 + j;
      int gci = ci * 64 + lane;
      int r = gci >> 3, cc = gci & 7;
      gl_lds16(Ag + ((size_t)(row0 + r) << 9) + kt * 64 + cc * 8, Al + ci * 512);
      gl_lds16(Bg + ((size_t)(col0 + r) << 9) + kt * 64 + cc * 8, Bl + ci * 512);
    }
    __syncthreads();
#pragma unroll
    for (int kk = 0; kk < 2; ++kk) {
      bf8 af[4], bb[4];
#pragma unroll
      for (int mf = 0; mf < 4; ++mf) {
        int r = wm * 64 + mf * 16 + cl;
        int cc = (kk * 4 + g) ^ (r & 7);
        af[mf] = *(const bf8*)(Al + r * 64 + cc * 8);
      }
#pragma unroll
      for (int nf = 0; nf < 4; ++nf) {
        int r = wn * 64 + nf * 16 + cl;
        int cc = (kk * 4 + g) ^ (r & 7);
        bb[nf] = *(const bf8*)(Bl + r * 64 + cc * 8);
      }
#pragma unroll
      for (int mf = 0; mf < 4; ++mf)
#pragma unroll
        for (int nf = 0; nf < 4; ++nf)
          acc[mf][nf] = __builtin_amdgcn_mfma_f32_16x16x32_bf16(af[mf], bb[nf], acc[mf][nf], 0, 0, 0);
    }
    __syncthreads();
  }

  if (EPI == 1) {
#pragma unroll
    for (int nf = 0; nf < 4; ++nf) {
      int col = col0 + wn * 64 + nf * 16 + cl;
      float bv = bias[col];
#pragma unroll
      for (int mf = 0; mf < 4; ++mf) {
#pragma unroll
        for (int j = 0; j < 4; ++j) {
          int row = row0 + wm * 64 + mf * 16 + 4 * g + j;  // C/D: col=lane&15, row=4*(lane>>4)+reg
          Of[((size_t)row << 9) + col] = acc[mf][nf][j] + bv;
        }
      }
    }
  } else {
    const int which = col0 >> 9;   // block-uniform
#pragma unroll
    for (int nf = 0; nf < 4; ++nf) {
      int col = col0 + wn * 64 + nf * 16 + cl;
      float bv = bias[col];
      int d = col & 63, h = (col >> 6) & 7;
#pragma unroll
      for (int mf = 0; mf < 4; ++mf) {
        int row = row0 + wm * 64 + mf * 16 + 4 * g;   // j = 0 row
        int b = row >> 11, s = row & 2047;
        size_t fb = ((size_t)b * 8 + h) * 131072;     // per-(b,h) fragment array
        if (which == 0) {
          // Q frag: [q16][kk][lane][8]; scale folds softmax 1/8 AND log2(e)
#pragma unroll
          for (int j = 0; j < 4; ++j) {
            int ss = s + j;
            size_t off = fb + (size_t)((ss >> 4) * 1024 + (d >> 5) * 512 +
                                       (((d >> 3) & 3) * 16 + (ss & 15)) * 8 + (d & 7));
            Oq[off] = f2bf((acc[mf][nf][j] + bv) * (0.125f * L2E));
          }
        } else if (which == 1) {
          // K frag: [kt][kk][ct][lane][8]
#pragma unroll
          for (int j = 0; j < 4; ++j) {
            int ss = s + j;
            size_t off = fb + (size_t)((ss >> 6) * 4096 + (d >> 5) * 2048 + ((ss >> 4) & 3) * 512 +
                                       (((d >> 3) & 3) * 16 + (ss & 15)) * 8 + (d & 7));
            Ok[off] = f2bf(acc[mf][nf][j] + bv);
          }
        } else {
          // V frag: [kt][kk][ct][lane][8]
          us4 o;
#pragma unroll
          for (int j = 0; j < 4; ++j) o[j] = f2bf(acc[mf][nf][j] + bv);
          size_t off = fb + (size_t)((s >> 6) * 4096 + ((s >> 5) & 1) * 2048 + (d >> 4) * 512 +
                                     ((((s >> 3) & 3) * 16) + (d & 15)) * 8 + (s & 7));
          *(us4*)(Ov + off) = o;
        }
      }
    }
  }
}

// ------------------------------- flash attention --------------------------------
// block = 4 waves = 4 BATCHES of the same (h, q16) slab; 2048 blocks big-first.
// SWAPPED tile body (lane owns q-row), exp2 softmax WITH defer-max,
// P via stride-72 LDS rows (addr-reg + offset: immediates; 2-way reads are free).
template <bool RELT>
__global__ __launch_bounds__(256, 4)
void k_attn(const unsigned short* __restrict__ Qf, const unsigned short* __restrict__ Kf,
            const unsigned short* __restrict__ Vf, const float* __restrict__ rel,
            const unsigned short* __restrict__ relt, unsigned short* __restrict__ AO) {
  __shared__ __align__(16) unsigned short Pl[4][16 * 72];
  const int tid = threadIdx.x, wv = tid >> 6, lane = tid & 63, g = lane >> 4, cl = lane & 15;
  int bid = blockIdx.x;                        // 2048 blocks
  int h = bid & 7;                             // head's relt panel pinned to one XCD
  int rest = bid >> 3;                         // 0..255
  int q16 = 127 - (rest >> 1);                 // 127..0, big-first
  int b = ((rest & 1) << 2) | wv;              // 0..7
  const int rX = q16 << 4;
  const int ktop = q16 >> 2;                   // diagonal k-tile index
  const int qrow = rX + cl;                    // this lane's q-row (swapped layout)
  size_t fb = (((size_t)b << 3) + h) * 131072;
  const unsigned short* Qp = Qf + fb;
  const unsigned short* Kp = Kf + fb;
  const unsigned short* Vp = Vf + fb;
  const float* relp = rel + ((size_t)h << 22);
  unsigned short* pw = Pl[wv];

  bf8 qf[2];
#pragma unroll
  for (int kk = 0; kk < 2; ++kk)
    qf[kk] = *(const bf8*)(Qp + q16 * 1024 + kk * 512 + lane * 8);

  f4 ot[4];                                    // O^T frags: ot[ct][j] = O[q=cl][d=16ct+4g+j]
  float mr = -1e30f, lr = 0.f;
#pragma unroll
  for (int ct = 0; ct < 4; ++ct) ot[ct] = (f4){0.f, 0.f, 0.f, 0.f};

  for (int kt = 0; kt <= ktop; ++kt) {
    const int kb = kt << 6;
    const unsigned short* Kt = Kp + kt * 4096;
    const unsigned short* Vt = Vp + kt * 4096;
    // ---- ALL loads up front: K (QK^T dep), then V, then rel (FIFO vmcnt) ----
    bf8 kf[2][4], vf[2][4];
#pragma unroll
    for (int kk = 0; kk < 2; ++kk)
#pragma unroll
      for (int ct = 0; ct < 4; ++ct)
        kf[kk][ct] = *(const bf8*)(Kt + kk * 2048 + ct * 512 + lane * 8);
#pragma unroll
    for (int kk = 0; kk < 2; ++kk)
#pragma unroll
      for (int ct = 0; ct < 4; ++ct)
        vf[kk][ct] = *(const bf8*)(Vt + kk * 2048 + ct * 512 + lane * 8);
    us4 rt4[4];
    float4 rl4[4];
    if constexpr (RELT) {
      const unsigned short* tb = relt + (((((size_t)h << 7) | q16) << 5) | kt) * 1024;
#pragma unroll
      for (int ct = 0; ct < 4; ++ct)
        rt4[ct] = *(const us4*)(tb + ((ct << 6) | lane) * 4);
    } else {
#pragma unroll
      for (int ct = 0; ct < 4; ++ct)
        rl4[ct] = *(const float4*)(relp + ((size_t)qrow << 11) + kb + ct * 16 + g * 4);
    }
    // ---- QK^T SWAPPED: st[ct][j] = S[q=cl][k = kb + 16ct + 4g + j] ----
    f4 st[4];
#pragma unroll
    for (int ct = 0; ct < 4; ++ct) st[ct] = (f4){0.f, 0.f, 0.f, 0.f};
#pragma unroll
    for (int kk = 0; kk < 2; ++kk)
#pragma unroll
      for (int ct = 0; ct < 4; ++ct)
        st[ct] = __builtin_amdgcn_mfma_f32_16x16x32_bf16(kf[kk][ct], qf[kk], st[ct], 0, 0, 0);
    // ---- rel_pos add (already in log2e domain) ----
    if constexpr (RELT) {
#pragma unroll
      for (int ct = 0; ct < 4; ++ct)
#pragma unroll
        for (int j = 0; j < 4; ++j)
          st[ct][j] += __builtin_bit_cast(float, (unsigned)rt4[ct][j] << 16);
    } else {
#pragma unroll
      for (int ct = 0; ct < 4; ++ct) {
        st[ct][0] = fmaf(rl4[ct].x, L2E, st[ct][0]);
        st[ct][1] = fmaf(rl4[ct].y, L2E, st[ct][1]);
        st[ct][2] = fmaf(rl4[ct].z, L2E, st[ct][2]);
        st[ct][3] = fmaf(rl4[ct].w, L2E, st[ct][3]);
      }
    }
    // ---- causal mask (diagonal tile only) ----
    if (kt == ktop) {
#pragma unroll
      for (int ct = 0; ct < 4; ++ct) {
        int kc0 = kb + ct * 16 + 4 * g;
#pragma unroll
        for (int j = 0; j < 4; ++j)
          if (kc0 + j > qrow) st[ct][j] = -1e30f;
      }
    }
    // ---- online softmax (exp2 domain) with defer-max (measured -2.4us) ----
    float m0 = fmaxf(fmaxf(st[0][0], st[0][1]), fmaxf(st[0][2], st[0][3]));
#pragma unroll
    for (int ct = 1; ct < 4; ++ct)
      m0 = fmaxf(m0, fmaxf(fmaxf(st[ct][0], st[ct][1]), fmaxf(st[ct][2], st[ct][3])));
    m0 = fmaxf(m0, __shfl_xor(m0, 16));
    m0 = fmaxf(m0, __shfl_xor(m0, 32));
    if (__any(m0 > mr + 11.54f)) {             // THR = 8*log2(e): P bounded by 2^11.54
      float mn = fmaxf(mr, m0);
      float al = exp2f(mr - mn);
      mr = mn;
      lr *= al;
#pragma unroll
      for (int ct = 0; ct < 4; ++ct) {
        ot[ct][0] *= al; ot[ct][1] *= al; ot[ct][2] *= al; ot[ct][3] *= al;
      }
    }
#pragma unroll
    for (int ct = 0; ct < 4; ++ct)
#pragma unroll
      for (int j = 0; j < 4; ++j) st[ct][j] = exp2f(st[ct][j] - mr);
    float rs = 0.f;
#pragma unroll
    for (int ct = 0; ct < 4; ++ct)
      rs += (st[ct][0] + st[ct][1]) + (st[ct][2] + st[ct][3]);
    rs += __shfl_xor(rs, 16);
    rs += __shfl_xor(rs, 32);
    lr += rs;
    // ---- P -> LDS rows [q=cl][k], stride 72 (one addr reg + offset: imm) ----
#pragma unroll
    for (int ct = 0; ct < 4; ++ct) {
      us4 pk;
      pk[0] = cbf(st[ct][0]); pk[1] = cbf(st[ct][1]);
      pk[2] = cbf(st[ct][2]); pk[3] = cbf(st[ct][3]);
      *(us4*)(pw + cl * 72 + ct * 16 + g * 4) = pk;
    }
    // ---- PV SWAPPED: ot[ct] += mfma(V_frag, P_frag); P read = B-frag b128 ----
#pragma unroll
    for (int kk = 0; kk < 2; ++kk) {
      bf8 pf = __builtin_bit_cast(bf8, *(const us8*)(pw + cl * 72 + kk * 32 + g * 8));
#pragma unroll
      for (int ct = 0; ct < 4; ++ct)
        ot[ct] = __builtin_amdgcn_mfma_f32_16x16x32_bf16(vf[kk][ct], pf, ot[ct], 0, 0, 0);
    }
  }
  // ---- epilogue: O /= l; d = 16ct+4g+j -> chunk-swizzled us4 stores ----
  float inv = 1.0f / lr;
  const int s = qrow;
  unsigned short* aor = AO + (((size_t)b << 11) + s) * 512 + h * 64;
#pragma unroll
  for (int ct = 0; ct < 4; ++ct) {
    int chunk = 2 * ct + (g >> 1);
    int base = (4 * (g & 1)) | ((chunk ^ (s & 7)) << 3);
    us4 o;
    o[0] = cbf(ot[ct][0] * inv); o[1] = cbf(ot[ct][1] * inv);
    o[2] = cbf(ot[ct][2] * inv); o[3] = cbf(ot[ct][3] * inv);
    *(us4*)(aor + base) = o;
  }
}

// ------------------------------------ launch ------------------------------------
extern "C" void kernel_launch(void* const* d_in, const int* in_sizes, int n_in,
                              void* d_out, int out_size, void* d_ws, size_t ws_size,
                              hipStream_t stream) {
  const float* x    = (const float*)d_in[0];
  const float* Wqkv = (const float*)d_in[1];
  const float* bqkv = (const float*)d_in[2];
  const float* Wout = (const float*)d_in[3];
  const float* bout = (const float*)d_in[4];
  const float* rel  = (const float*)d_in[5];
  float* out = (float*)d_out;

  unsigned short* Qw  = (unsigned short*)d_ws;
  unsigned short* Kw  = Qw  + 8388608;
  unsigned short* Vw  = Kw  + 8388608;
  unsigned short* XA  = Vw  + 8388608;    // Xb (pre-attn) then AO (post-attn)
  unsigned short* WtQ = XA  + 8388608;
  unsigned short* WtO = WtQ + 786432;
  unsigned short* relt= WtO + 262144;
  const bool useT = ws_size >= (34603008ULL + 33554432ULL) * 2ULL;  // base + rel table

  k_convert_x<<<dim3(4096), dim3(256), 0, stream>>>(x, XA);
  k_transpose_w<<<dim3(16, 48), dim3(256), 0, stream>>>(Wqkv, WtQ, 1536);
  k_transpose_w<<<dim3(16, 16), dim3(256), 0, stream>>>(Wout, WtO, 512);
  if (useT) k_relconv<<<dim3(8192), dim3(256), 0, stream>>>(rel, relt);
  k_gemm<0><<<dim3(128, 12), dim3(256), 0, stream>>>(XA, WtQ, bqkv, nullptr, Qw, Kw, Vw);
  if (useT) k_attn<true ><<<dim3(2048), dim3(256), 0, stream>>>(Qw, Kw, Vw, rel, relt, XA);
  else      k_attn<false><<<dim3(2048), dim3(256), 0, stream>>>(Qw, Kw, Vw, rel, relt, XA);
  k_gemm<1><<<dim3(128, 4), dim3(256), 0, stream>>>(XA, WtO, bout, out, nullptr, nullptr, nullptr);
}

// Round 25
// 194.834 us; speedup vs baseline: 1.0332x; 1.0086x over previous
//
#include <hip/hip_runtime.h>
#include <cstdint>

// CausalSelfAttention fused pipeline, all-bf16 MFMA path. FINAL COMPOSITION:
// R25 = R20's attn body VERBATIM (best single measurement: 104.4us — swapped-QK^T,
// stride-72 P-LDS, exp2 softmax with unconditional rescale, 4-batch-wave grid,
// relt L1-sharing, launch_bounds(256,4)) + R21's coalesced relconv (the one
// non-attn win since R17). Attn variants R18-R24 all landed in the 104-110us
// noise band; this composes the two best-measured components with no new code.
// ws layout (ushort): Qf[8.39M] Kf[8.39M] Vf[8.39M] XbAO[8.39M] WtQ[786K] WtO[262K] [relt 33.55M]

#define DEVI __device__ __forceinline__

typedef __bf16 bf8 __attribute__((ext_vector_type(8)));
typedef float f4 __attribute__((ext_vector_type(4)));
typedef unsigned short us8 __attribute__((ext_vector_type(8)));
typedef unsigned short us4 __attribute__((ext_vector_type(4)));

typedef const unsigned int __attribute__((address_space(1))) gu32;
typedef unsigned int __attribute__((address_space(3))) lu32;

#define L2E 1.44269504088896f

DEVI unsigned short f2bf(float f) {  // RNE f32->bf16 (prep/GEMM epilogues)
  unsigned u = __builtin_bit_cast(unsigned, f);
  u += 0x7fffu + ((u >> 16) & 1u);
  return (unsigned short)(u >> 16);
}

DEVI unsigned short cbf(float f) {   // compiler-lowered cast (v_cvt_pk_bf16_f32 pairs)
  return __builtin_bit_cast(unsigned short, (__bf16)f);
}

DEVI void gl_lds16(const void* g, void* l) {
  __builtin_amdgcn_global_load_lds((gu32*)g, (lu32*)l, 16, 0, 0);
}

// ---------------- prep: x (f32 [16384][512]) -> bf16, chunk-swizzled ----------------
__global__ __launch_bounds__(256) void k_convert_x(const float* __restrict__ x,
                                                   unsigned short* __restrict__ xb) {
  int c = blockIdx.x * 256 + threadIdx.x;   // 1,048,576 chunks
  int row = c >> 6, cl = c & 63;
  const float* s = x + ((size_t)row << 9) + (cl << 3);
  float4 a = *(const float4*)s;
  float4 b = *(const float4*)(s + 4);
  us8 o;
  o[0]=f2bf(a.x); o[1]=f2bf(a.y); o[2]=f2bf(a.z); o[3]=f2bf(a.w);
  o[4]=f2bf(b.x); o[5]=f2bf(b.y); o[6]=f2bf(b.z); o[7]=f2bf(b.w);
  int p = (cl & ~7) | ((cl & 7) ^ (row & 7));
  *(us8*)(xb + ((size_t)row << 9) + (p << 3)) = o;
}

// ------------- prep: W [512][N] f32 -> Wt [N][512] bf16, chunk-swizzled -------------
__global__ __launch_bounds__(256) void k_transpose_w(const float* __restrict__ W,
                                                     unsigned short* __restrict__ Wt, int N) {
  __shared__ float t[32][33];
  int k0 = blockIdx.x * 32, n0 = blockIdx.y * 32;
  int tx = threadIdx.x & 31, ty = threadIdx.x >> 5;
#pragma unroll
  for (int r = 0; r < 4; ++r)
    t[ty + r * 8][tx] = W[(size_t)(k0 + ty + r * 8) * N + n0 + tx];
  __syncthreads();
#pragma unroll
  for (int r = 0; r < 4; ++r) {
    int n = n0 + ty + r * 8, k = k0 + tx;
    int k2 = (k & ~63) | ((((k >> 3) & 7) ^ (n & 7)) << 3) | (k & 7);
    Wt[((size_t)n << 9) + k2] = f2bf(t[tx][ty + r * 8]);
  }
}

// ---- prep: rel f32 [h][q][k] -> bf16 table, SWAPPED frag order, PRE-SCALED by log2e ----
// One WAVE per (h,q16,kt) tile: coalesced 16x(256B) row reads -> wave-private LDS
// -> transpose reads -> coalesced us4 writes.
__global__ __launch_bounds__(256) void k_relconv(const float* __restrict__ rel,
                                                 unsigned short* __restrict__ relt) {
  __shared__ __align__(16) float tl[4][16][68];
  int wv = threadIdx.x >> 6, lane = threadIdx.x & 63;
  int t = blockIdx.x * 4 + wv;              // 32768 tiles
  int kt = t & 31, q16 = (t >> 5) & 127, h = t >> 12;
  if (kt > (q16 >> 2)) return;              // above-diagonal tiles never read
  const float* src = rel + ((size_t)h << 22) +
                     ((size_t)((q16 << 4) + (lane >> 2)) << 11) + (kt << 6) + (lane & 3) * 16;
  float4 v0 = *(const float4*)(src);
  float4 v1 = *(const float4*)(src + 4);
  float4 v2 = *(const float4*)(src + 8);
  float4 v3 = *(const float4*)(src + 12);
  float* dst = &tl[wv][lane >> 2][(lane & 3) * 16];
  *(float4*)(dst) = v0; *(float4*)(dst + 4) = v1;
  *(float4*)(dst + 8) = v2; *(float4*)(dst + 12) = v3;
  size_t tb = (((((size_t)h << 7) | q16) << 5) | kt) << 2;
#pragma unroll
  for (int ct = 0; ct < 4; ++ct) {
    const float* rp = &tl[wv][lane & 15][ct * 16 + ((lane >> 4) << 2)];
    float4 rv = *(const float4*)rp;
    us4 o;
    o[0] = f2bf(rv.x * L2E); o[1] = f2bf(rv.y * L2E);
    o[2] = f2bf(rv.z * L2E); o[3] = f2bf(rv.w * L2E);
    *(us4*)(relt + (((tb | ct) << 6) | lane) * 4) = o;
  }
}

// ---------------- GEMM: C[M][col] = A[M][512] * Bt[col][512]^T + bias ----------------
template <int EPI>
__global__ __launch_bounds__(256, 2)
void k_gemm(const unsigned short* __restrict__ Ag, const unsigned short* __restrict__ Bg,
            const float* __restrict__ bias, float* __restrict__ Of,
            unsigned short* __restrict__ Oq, unsigned short* __restrict__ Ok,
            unsigned short* __restrict__ Ov) {
  __shared__ __align__(16) unsigned short lds[128 * 64 * 2];
  unsigned short* Al = lds;
  unsigned short* Bl = lds + 128 * 64;
  const int tid = threadIdx.x, wv = tid >> 6, lane = tid & 63, g = lane >> 4, cl = lane & 15;
  const int wm = wv >> 1, wn = wv & 1;
  const int row0 = blockIdx.x * 128, col0 = blockIdx.y * 128;
  f4 acc[4][4];
#pragma unroll
  for (int i = 0; i < 4; ++i)
#pragma unroll
    for (int j = 0; j < 4; ++j) acc[i][j] = (f4){0.f, 0.f, 0.f, 0.f};

  for (int kt = 0; kt < 8; ++kt) {
#pragma unroll
    for (int j = 0; j < 4; ++j) {
      int ci = wv * 4 + j;
      int gci = ci * 64 + lane;
      int r = gci >> 3, cc = gci & 7;
      gl_lds16(Ag + ((size_t)(row0 + r) << 9) + kt * 64 + cc * 8, Al + ci * 512);
      gl_lds16(Bg + ((size_t)(col0 + r) << 9) + kt * 64 + cc * 8, Bl + ci * 512);
    }
    __syncthreads();
#pragma unroll
    for (int kk = 0; kk < 2; ++kk) {
      bf8 af[4], bb[4];
#pragma unroll
      for (int mf = 0; mf < 4; ++mf) {
        int r = wm * 64 + mf * 16 + cl;
        int cc = (kk * 4 + g) ^ (r & 7);
        af[mf] = *(const bf8*)(Al + r * 64 + cc * 8);
      }
#pragma unroll
      for (int nf = 0; nf < 4; ++nf) {
        int r = wn * 64 + nf * 16 + cl;
        int cc = (kk * 4 + g) ^ (r & 7);
        bb[nf] = *(const bf8*)(Bl + r * 64 + cc * 8);
      }
#pragma unroll
      for (int mf = 0; mf < 4; ++mf)
#pragma unroll
        for (int nf = 0; nf < 4; ++nf)
          acc[mf][nf] = __builtin_amdgcn_mfma_f32_16x16x32_bf16(af[mf], bb[nf], acc[mf][nf], 0, 0, 0);
    }
    __syncthreads();
  }

  if (EPI == 1) {
#pragma unroll
    for (int nf = 0; nf < 4; ++nf) {
      int col = col0 + wn * 64 + nf * 16 + cl;
      float bv = bias[col];
#pragma unroll
      for (int mf = 0; mf < 4; ++mf) {
#pragma unroll
        for (int j = 0; j < 4; ++j) {
          int row = row0 + wm * 64 + mf * 16 + 4 * g + j;  // C/D: col=lane&15, row=4*(lane>>4)+reg
          Of[((size_t)row << 9) + col] = acc[mf][nf][j] + bv;
        }
      }
    }
  } else {
    const int which = col0 >> 9;   // block-uniform
#pragma unroll
    for (int nf = 0; nf < 4; ++nf) {
      int col = col0 + wn * 64 + nf * 16 + cl;
      float bv = bias[col];
      int d = col & 63, h = (col >> 6) & 7;
#pragma unroll
      for (int mf = 0; mf < 4; ++mf) {
        int row = row0 + wm * 64 + mf * 16 + 4 * g;   // j = 0 row
        int b = row >> 11, s = row & 2047;
        size_t fb = ((size_t)b * 8 + h) * 131072;     // per-(b,h) fragment array
        if (which == 0) {
          // Q frag: [q16][kk][lane][8]; scale folds softmax 1/8 AND log2(e)
#pragma unroll
          for (int j = 0; j < 4; ++j) {
            int ss = s + j;
            size_t off = fb + (size_t)((ss >> 4) * 1024 + (d >> 5) * 512 +
                                       (((d >> 3) & 3) * 16 + (ss & 15)) * 8 + (d & 7));
            Oq[off] = f2bf((acc[mf][nf][j] + bv) * (0.125f * L2E));
          }
        } else if (which == 1) {
          // K frag: [kt][kk][ct][lane][8]
#pragma unroll
          for (int j = 0; j < 4; ++j) {
            int ss = s + j;
            size_t off = fb + (size_t)((ss >> 6) * 4096 + (d >> 5) * 2048 + ((ss >> 4) & 3) * 512 +
                                       (((d >> 3) & 3) * 16 + (ss & 15)) * 8 + (d & 7));
            Ok[off] = f2bf(acc[mf][nf][j] + bv);
          }
        } else {
          // V frag: [kt][kk][ct][lane][8]
          us4 o;
#pragma unroll
          for (int j = 0; j < 4; ++j) o[j] = f2bf(acc[mf][nf][j] + bv);
          size_t off = fb + (size_t)((s >> 6) * 4096 + ((s >> 5) & 1) * 2048 + (d >> 4) * 512 +
                                     ((((s >> 3) & 3) * 16) + (d & 15)) * 8 + (s & 7));
          *(us4*)(Ov + off) = o;
        }
      }
    }
  }
}

// ------------------------------- flash attention --------------------------------
// block = 4 waves = 4 BATCHES of the same (h, q16) slab; 2048 blocks big-first.
// SWAPPED tile body: st = mfma(K,Q) -> lane owns q-row (q=cl), k=16ct+4g+j.
// Softmax (exp2 domain, unconditional rescale): in-lane trees + 2 shfl.
// P via stride-72 LDS rows: 4 ds_write_b64 + 2 ds_read_b128. PV: ot = mfma(V,P).
template <bool RELT>
__global__ __launch_bounds__(256, 4)
void k_attn(const unsigned short* __restrict__ Qf, const unsigned short* __restrict__ Kf,
            const unsigned short* __restrict__ Vf, const float* __restrict__ rel,
            const unsigned short* __restrict__ relt, unsigned short* __restrict__ AO) {
  __shared__ __align__(16) unsigned short Pl[4][16 * 72];
  const int tid = threadIdx.x, wv = tid >> 6, lane = tid & 63, g = lane >> 4, cl = lane & 15;
  int bid = blockIdx.x;                        // 2048 blocks
  int h = bid & 7;                             // head's relt panel pinned to one XCD
  int rest = bid >> 3;                         // 0..255
  int q16 = 127 - (rest >> 1);                 // 127..0, big-first
  int b = ((rest & 1) << 2) | wv;              // 0..7
  const int rX = q16 << 4;
  const int ktop = q16 >> 2;                   // diagonal k-tile index
  const int qrow = rX + cl;                    // this lane's q-row (swapped layout)
  size_t fb = (((size_t)b << 3) + h) * 131072;
  const unsigned short* Qp = Qf + fb;
  const unsigned short* Kp = Kf + fb;
  const unsigned short* Vp = Vf + fb;
  const float* relp = rel + ((size_t)h << 22);
  unsigned short* pw = Pl[wv];

  bf8 qf[2];
#pragma unroll
  for (int kk = 0; kk < 2; ++kk)
    qf[kk] = *(const bf8*)(Qp + q16 * 1024 + kk * 512 + lane * 8);

  f4 ot[4];                                    // O^T frags: ot[ct][j] = O[q=cl][d=16ct+4g+j]
  float mr = -1e30f, lr = 0.f;
#pragma unroll
  for (int ct = 0; ct < 4; ++ct) ot[ct] = (f4){0.f, 0.f, 0.f, 0.f};

  for (int kt = 0; kt <= ktop; ++kt) {
    const int kb = kt << 6;
    const unsigned short* Kt = Kp + kt * 4096;
    const unsigned short* Vt = Vp + kt * 4096;
    // ---- ALL loads up front: K (QK^T dep), then V, then rel (FIFO vmcnt) ----
    bf8 kf[2][4], vf[2][4];
#pragma unroll
    for (int kk = 0; kk < 2; ++kk)
#pragma unroll
      for (int ct = 0; ct < 4; ++ct)
        kf[kk][ct] = *(const bf8*)(Kt + kk * 2048 + ct * 512 + lane * 8);
#pragma unroll
    for (int kk = 0; kk < 2; ++kk)
#pragma unroll
      for (int ct = 0; ct < 4; ++ct)
        vf[kk][ct] = *(const bf8*)(Vt + kk * 2048 + ct * 512 + lane * 8);
    us4 rt4[4];
    float4 rl4[4];
    if constexpr (RELT) {
      const unsigned short* tb = relt + (((((size_t)h << 7) | q16) << 5) | kt) * 1024;
#pragma unroll
      for (int ct = 0; ct < 4; ++ct)
        rt4[ct] = *(const us4*)(tb + ((ct << 6) | lane) * 4);
    } else {
#pragma unroll
      for (int ct = 0; ct < 4; ++ct)
        rl4[ct] = *(const float4*)(relp + ((size_t)qrow << 11) + kb + ct * 16 + g * 4);
    }
    // ---- QK^T SWAPPED: st[ct][j] = S[q=cl][k = kb + 16ct + 4g + j] ----
    f4 st[4];
#pragma unroll
    for (int ct = 0; ct < 4; ++ct) st[ct] = (f4){0.f, 0.f, 0.f, 0.f};
#pragma unroll
    for (int kk = 0; kk < 2; ++kk)
#pragma unroll
      for (int ct = 0; ct < 4; ++ct)
        st[ct] = __builtin_amdgcn_mfma_f32_16x16x32_bf16(kf[kk][ct], qf[kk], st[ct], 0, 0, 0);
    // ---- rel_pos add (already in log2e domain) ----
    if constexpr (RELT) {
#pragma unroll
      for (int ct = 0; ct < 4; ++ct)
#pragma unroll
        for (int j = 0; j < 4; ++j)
          st[ct][j] += __builtin_bit_cast(float, (unsigned)rt4[ct][j] << 16);
    } else {
#pragma unroll
      for (int ct = 0; ct < 4; ++ct) {
        st[ct][0] = fmaf(rl4[ct].x, L2E, st[ct][0]);
        st[ct][1] = fmaf(rl4[ct].y, L2E, st[ct][1]);
        st[ct][2] = fmaf(rl4[ct].z, L2E, st[ct][2]);
        st[ct][3] = fmaf(rl4[ct].w, L2E, st[ct][3]);
      }
    }
    // ---- causal mask (diagonal tile only) ----
    if (kt == ktop) {
#pragma unroll
      for (int ct = 0; ct < 4; ++ct) {
        int kc0 = kb + ct * 16 + 4 * g;
#pragma unroll
        for (int j = 0; j < 4; ++j)
          if (kc0 + j > qrow) st[ct][j] = -1e30f;
      }
    }
    // ---- online softmax (exp2 domain, unconditional rescale) ----
    float m0 = fmaxf(fmaxf(st[0][0], st[0][1]), fmaxf(st[0][2], st[0][3]));
#pragma unroll
    for (int ct = 1; ct < 4; ++ct)
      m0 = fmaxf(m0, fmaxf(fmaxf(st[ct][0], st[ct][1]), fmaxf(st[ct][2], st[ct][3])));
    m0 = fmaxf(m0, __shfl_xor(m0, 16));
    m0 = fmaxf(m0, __shfl_xor(m0, 32));
    float mn = fmaxf(mr, m0);
    float al = exp2f(mr - mn);
    mr = mn;
#pragma unroll
    for (int ct = 0; ct < 4; ++ct)
#pragma unroll
      for (int j = 0; j < 4; ++j) st[ct][j] = exp2f(st[ct][j] - mn);
    float rs = 0.f;
#pragma unroll
    for (int ct = 0; ct < 4; ++ct)
      rs += (st[ct][0] + st[ct][1]) + (st[ct][2] + st[ct][3]);
    rs += __shfl_xor(rs, 16);
    rs += __shfl_xor(rs, 32);
    lr = lr * al + rs;
#pragma unroll
    for (int ct = 0; ct < 4; ++ct) {
      ot[ct][0] *= al; ot[ct][1] *= al; ot[ct][2] *= al; ot[ct][3] *= al;
    }
    // ---- P -> LDS rows [q=cl][k], stride 72 (one addr reg + offset: imm) ----
#pragma unroll
    for (int ct = 0; ct < 4; ++ct) {
      us4 pk;
      pk[0] = cbf(st[ct][0]); pk[1] = cbf(st[ct][1]);
      pk[2] = cbf(st[ct][2]); pk[3] = cbf(st[ct][3]);
      *(us4*)(pw + cl * 72 + ct * 16 + g * 4) = pk;
    }
    // ---- PV SWAPPED: ot[ct] += mfma(V_frag, P_frag); P read = B-frag b128 ----
#pragma unroll
    for (int kk = 0; kk < 2; ++kk) {
      bf8 pf = __builtin_bit_cast(bf8, *(const us8*)(pw + cl * 72 + kk * 32 + g * 8));
#pragma unroll
      for (int ct = 0; ct < 4; ++ct)
        ot[ct] = __builtin_amdgcn_mfma_f32_16x16x32_bf16(vf[kk][ct], pf, ot[ct], 0, 0, 0);
    }
  }
  // ---- epilogue: O /= l; d = 16ct+4g+j -> chunk-swizzled us4 stores ----
  float inv = 1.0f / lr;
  const int s = qrow;
  unsigned short* aor = AO + (((size_t)b << 11) + s) * 512 + h * 64;
#pragma unroll
  for (int ct = 0; ct < 4; ++ct) {
    int chunk = 2 * ct + (g >> 1);
    int base = (4 * (g & 1)) | ((chunk ^ (s & 7)) << 3);
    us4 o;
    o[0] = cbf(ot[ct][0] * inv); o[1] = cbf(ot[ct][1] * inv);
    o[2] = cbf(ot[ct][2] * inv); o[3] = cbf(ot[ct][3] * inv);
    *(us4*)(aor + base) = o;
  }
}

// ------------------------------------ launch ------------------------------------
extern "C" void kernel_launch(void* const* d_in, const int* in_sizes, int n_in,
                              void* d_out, int out_size, void* d_ws, size_t ws_size,
                              hipStream_t stream) {
  const float* x    = (const float*)d_in[0];
  const float* Wqkv = (const float*)d_in[1];
  const float* bqkv = (const float*)d_in[2];
  const float* Wout = (const float*)d_in[3];
  const float* bout = (const float*)d_in[4];
  const float* rel  = (const float*)d_in[5];
  float* out = (float*)d_out;

  unsigned short* Qw  = (unsigned short*)d_ws;
  unsigned short* Kw  = Qw  + 8388608;
  unsigned short* Vw  = Kw  + 8388608;
  unsigned short* XA  = Vw  + 8388608;    // Xb (pre-attn) then AO (post-attn)
  unsigned short* WtQ = XA  + 8388608;
  unsigned short* WtO = WtQ + 786432;
  unsigned short* relt= WtO + 262144;
  const bool useT = ws_size >= (34603008ULL + 33554432ULL) * 2ULL;  // base + rel table

  k_convert_x<<<dim3(4096), dim3(256), 0, stream>>>(x, XA);
  k_transpose_w<<<dim3(16, 48), dim3(256), 0, stream>>>(Wqkv, WtQ, 1536);
  k_transpose_w<<<dim3(16, 16), dim3(256), 0, stream>>>(Wout, WtO, 512);
  if (useT) k_relconv<<<dim3(8192), dim3(256), 0, stream>>>(rel, relt);
  k_gemm<0><<<dim3(128, 12), dim3(256), 0, stream>>>(XA, WtQ, bqkv, nullptr, Qw, Kw, Vw);
  if (useT) k_attn<true ><<<dim3(2048), dim3(256), 0, stream>>>(Qw, Kw, Vw, rel, relt, XA);
  else      k_attn<false><<<dim3(2048), dim3(256), 0, stream>>>(Qw, Kw, Vw, rel, relt, XA);
  k_gemm<1><<<dim3(128, 4), dim3(256), 0, stream>>>(XA, WtO, bout, out, nullptr, nullptr, nullptr);
}